// Round 7
// baseline (152.423 us; speedup 1.0000x reference)
//
#include <hip/hip_runtime.h>
#include <stdint.h>

// Problem constants
#define NN 4096
#define KSEL 1677721u            // int(4096*4096*0.1)
#define INV_SQRT_DK 0.17677669529663687f  // 1/sqrt(32)

// Workspace layout (bytes)
#define OFF_P0 0                      // Qpart fp32 [2][4096*128] = 4 MB (dead after combine)
#define OFF_P2 (4u<<20)               // Kpart fp32 [2][4096*128] = 4 MB
#define OFF_QH (8u<<20)               // bf16 1 MB each
#define OFF_QL (9u<<20)
#define OFF_KH (10u<<20)
#define OFF_KL (11u<<20)
#define OFF_STATS (12u<<20)           // 4096 * float2 = 32 KB
// hist reuses the dead Qp-partial region (written only after combine):
#define OFF_H  0u                     // 256 partial hists x 1024 u32 = 1 MB
#define OFF_ST (1u<<20)               // state: 4 u32
#define HALF_ELEMS 524288u            // 4096*128

typedef __attribute__((ext_vector_type(8))) short bf16x8;
typedef __attribute__((ext_vector_type(4))) float f32x4;

static __device__ __forceinline__ short f2bf(float f) {
    unsigned u = __float_as_uint(f);
    unsigned r = (u + 0x7FFFu + ((u >> 16) & 1u)) >> 16;   // RNE
    return (short)r;
}
static __device__ __forceinline__ float bf2f(short h) {
    return __uint_as_float(((unsigned)(unsigned short)h) << 16);
}

// ---------------------------------------------------------------------------
// 1) Projection partial sums (fp32). Grid 512 = b(4) x ntile(64) x fhalf(2).
// ---------------------------------------------------------------------------
__global__ __launch_bounds__(512, 4) void proj_kernel(
    const float* __restrict__ x, const float* __restrict__ WQ,
    const float* __restrict__ WK,
    float* __restrict__ Qp, float* __restrict__ Kp)
{
    __shared__ float red[8 * 64 * 17];
    const int bx  = blockIdx.x;
    const int b   = bx >> 7;
    const int n0  = ((bx >> 1) & 63) << 6;
    const int fs  = bx & 1;
    const int tid = threadIdx.x;
    const int l   = tid & 63;
    const int w   = __builtin_amdgcn_readfirstlane(tid >> 6);
    const int n   = n0 + l;

    float* __restrict__ Qdst = Qp + (size_t)fs * HALF_ELEMS;
    float* __restrict__ Kdst = Kp + (size_t)fs * HALF_ELEMS;

    float accQ[32], accK[32];
#pragma unroll
    for (int j = 0; j < 32; ++j) { accQ[j] = 0.f; accK[j] = 0.f; }

    const int fg0 = fs * 32 + w * 4;
    const float* xp = x + (size_t)b * 3145728 + (size_t)fg0 * 49152 + (size_t)n * 12;

    for (int f = 0; f < 4; ++f) {
        float4 a0 = *(const float4*)(xp);
        float4 a1 = *(const float4*)(xp + 4);
        float4 a2 = *(const float4*)(xp + 8);
        const float xv[12] = {a0.x, a0.y, a0.z, a0.w,
                              a1.x, a1.y, a1.z, a1.w,
                              a2.x, a2.y, a2.z, a2.w};
        const int fg = fg0 + f;
#pragma unroll
        for (int t = 0; t < 12; ++t) {
            const float* __restrict__ wq = WQ + (size_t)(((t << 6) + fg) << 5);
            const float* __restrict__ wk = WK + (size_t)(((t << 6) + fg) << 5);
            const float xt = xv[t];
#pragma unroll
            for (int j = 0; j < 32; ++j) {
                accQ[j] = fmaf(xt, wq[j], accQ[j]);
                accK[j] = fmaf(xt, wk[j], accK[j]);
            }
        }
        xp += 49152;
    }

    for (int p = 0; p < 4; ++p) {
        const float* src = (p < 2) ? accQ : accK;
        const int off = (p & 1) << 4;
        float* rp = &red[(w * 64 + l) * 17];
#pragma unroll
        for (int j = 0; j < 16; ++j) rp[j] = src[off + j];
        __syncthreads();
#pragma unroll
        for (int h = 0; h < 2; ++h) {
            int o = tid + h * 512;
            int r_ = o >> 4, c = o & 15;
            float s = 0.f;
#pragma unroll
            for (int w2 = 0; w2 < 8; ++w2) s += red[(w2 * 64 + r_) * 17 + c];
            size_t idx = (size_t)(n0 + r_) * 128 + (b << 5) + ((p & 1) << 4) + c;
            if (p < 2) Qdst[idx] = s; else Kdst[idx] = s;
        }
        __syncthreads();
    }
}

// ---------------------------------------------------------------------------
// 1b) Combine f-halves, scale Q, split to bf16 hi/lo. Grid 512x256.
// ---------------------------------------------------------------------------
__global__ __launch_bounds__(256) void combine_kernel(
    const float4* __restrict__ Qp, const float4* __restrict__ Kp,
    short* __restrict__ Qhi, short* __restrict__ Qlo,
    short* __restrict__ Khi, short* __restrict__ Klo)
{
    const size_t i = (size_t)blockIdx.x * 256 + threadIdx.x;  // float4 slots
    float4 q0 = Qp[i], q1 = Qp[i + HALF_ELEMS / 4];
    float4 k0 = Kp[i], k1 = Kp[i + HALF_ELEMS / 4];
    float q[4] = {(q0.x + q1.x) * INV_SQRT_DK, (q0.y + q1.y) * INV_SQRT_DK,
                  (q0.z + q1.z) * INV_SQRT_DK, (q0.w + q1.w) * INV_SQRT_DK};
    float k[4] = {k0.x + k1.x, k0.y + k1.y, k0.z + k1.z, k0.w + k1.w};
    short4 qh, ql, kh, kl;
    qh.x = f2bf(q[0]); ql.x = f2bf(q[0] - bf2f(qh.x));
    qh.y = f2bf(q[1]); ql.y = f2bf(q[1] - bf2f(qh.y));
    qh.z = f2bf(q[2]); ql.z = f2bf(q[2] - bf2f(qh.z));
    qh.w = f2bf(q[3]); ql.w = f2bf(q[3] - bf2f(qh.w));
    kh.x = f2bf(k[0]); kl.x = f2bf(k[0] - bf2f(kh.x));
    kh.y = f2bf(k[1]); kl.y = f2bf(k[1] - bf2f(kh.y));
    kh.z = f2bf(k[2]); kl.z = f2bf(k[2] - bf2f(kh.z));
    kh.w = f2bf(k[3]); kl.w = f2bf(k[3] - bf2f(kh.w));
    *(short4*)(Qhi + 4 * i) = qh;
    *(short4*)(Qlo + 4 * i) = ql;
    *(short4*)(Khi + 4 * i) = kh;
    *(short4*)(Klo + 4 * i) = kl;
}

// ---------------------------------------------------------------------------
// 2) S = Q @ K^T via MFMA 16x16x32 bf16, 3-product hi/lo split.
//    128x128 tile per 512-thread block, 8 waves, wave tile 64x32 (4x2 frags):
//    fewer loads/wave + ~4 waves/SIMD to hide L2 latency (was 38.8us
//    latency-bound at 256thr/4waves).
// ---------------------------------------------------------------------------
__global__ __launch_bounds__(512, 4) void gemm_kernel(
    const short* __restrict__ Qhi, const short* __restrict__ Qlo,
    const short* __restrict__ Khi, const short* __restrict__ Klo,
    float* __restrict__ S)
{
    const int bi = blockIdx.x >> 5, bj = blockIdx.x & 31;
    const int tid = threadIdx.x;
    const int w = tid >> 6, l = tid & 63;
    const int wr = w >> 2, wc = w & 3;
    const int m0 = bi * 128 + wr * 64;
    const int n0 = bj * 128 + wc * 32;
    const int lr = l & 15;
    const int kg = (l >> 4) * 8;

    f32x4 acc[4][2];
#pragma unroll
    for (int i = 0; i < 4; ++i)
#pragma unroll
        for (int j = 0; j < 2; ++j) acc[i][j] = (f32x4){0.f, 0.f, 0.f, 0.f};

    for (int k0 = 0; k0 < 128; k0 += 32) {
        bf16x8 ah[4], al[4], bh[2], bl[2];
#pragma unroll
        for (int i = 0; i < 4; ++i) {
            size_t qo = (size_t)(m0 + i * 16 + lr) * 128 + k0 + kg;
            ah[i] = *(const bf16x8*)(Qhi + qo);
            al[i] = *(const bf16x8*)(Qlo + qo);
        }
#pragma unroll
        for (int j = 0; j < 2; ++j) {
            size_t ko = (size_t)(n0 + j * 16 + lr) * 128 + k0 + kg;
            bh[j] = *(const bf16x8*)(Khi + ko);
            bl[j] = *(const bf16x8*)(Klo + ko);
        }
#pragma unroll
        for (int i = 0; i < 4; ++i)
#pragma unroll
            for (int j = 0; j < 2; ++j) {
                acc[i][j] = __builtin_amdgcn_mfma_f32_16x16x32_bf16(ah[i], bh[j], acc[i][j], 0, 0, 0);
                acc[i][j] = __builtin_amdgcn_mfma_f32_16x16x32_bf16(ah[i], bl[j], acc[i][j], 0, 0, 0);
                acc[i][j] = __builtin_amdgcn_mfma_f32_16x16x32_bf16(al[i], bh[j], acc[i][j], 0, 0, 0);
            }
    }

    // C/D mapping (m89-verified): col = lane&15, row = (lane>>4)*4 + reg
#pragma unroll
    for (int i = 0; i < 4; ++i) {
        int rowb = m0 + i * 16 + (l >> 4) * 4;
#pragma unroll
        for (int j = 0; j < 2; ++j) {
            int col = n0 + j * 16 + (l & 15);
#pragma unroll
            for (int r = 0; r < 4; ++r)
                S[(size_t)(rowb + r) * NN + col] = acc[i][j][r];
        }
    }
}

// ---------------------------------------------------------------------------
// 3) Fused row stats + histogram. One wave per row, row in registers.
//    Each block OWNS partial-hist slot blockIdx.x: plain full overwrite,
//    so no memset of the hist region is needed (was 39us of fillBuffer).
// ---------------------------------------------------------------------------
__global__ __launch_bounds__(512) void histstat_kernel(
    const float* __restrict__ S, float2* __restrict__ stats,
    unsigned* __restrict__ gh)
{
    __shared__ unsigned h[1024];
    const int tid = threadIdx.x;
    const int l = tid & 63;
    const int w = tid >> 6;

    for (int i = tid; i < 1024; i += 512) h[i] = 0;
    __syncthreads();

#pragma unroll
    for (int r = 0; r < 2; ++r) {
        const int row = (blockIdx.x << 4) + (r << 3) + w;
        const float4* rp = (const float4*)(S + (size_t)row * NN);

        float4 v[16];
#pragma unroll
        for (int j = 0; j < 16; ++j) v[j] = rp[l + (j << 6)];

        float m = -3.4e38f;
#pragma unroll
        for (int j = 0; j < 16; ++j)
            m = fmaxf(m, fmaxf(fmaxf(v[j].x, v[j].y), fmaxf(v[j].z, v[j].w)));
#pragma unroll
        for (int off = 32; off; off >>= 1) m = fmaxf(m, __shfl_xor(m, off));

        float s = 0.f;
#pragma unroll
        for (int j = 0; j < 16; ++j) {
            v[j].x = __expf(v[j].x - m); v[j].y = __expf(v[j].y - m);
            v[j].z = __expf(v[j].z - m); v[j].w = __expf(v[j].w - m);
            s += (v[j].x + v[j].y) + (v[j].z + v[j].w);
        }
#pragma unroll
        for (int off = 32; off; off >>= 1) s += __shfl_xor(s, off);
        const float inv = 1.0f / s;
        if (l == 0) stats[row] = make_float2(m, inv);

#pragma unroll
        for (int j = 0; j < 16; ++j) {
            int b0 = min(max((int)(__float_as_uint(v[j].x * inv) >> 16) - 0x3780, 0), 1023);
            int b1 = min(max((int)(__float_as_uint(v[j].y * inv) >> 16) - 0x3780, 0), 1023);
            int b2 = min(max((int)(__float_as_uint(v[j].z * inv) >> 16) - 0x3780, 0), 1023);
            int b3 = min(max((int)(__float_as_uint(v[j].w * inv) >> 16) - 0x3780, 0), 1023);
            atomicAdd(&h[b0], 1u); atomicAdd(&h[b1], 1u);
            atomicAdd(&h[b2], 1u); atomicAdd(&h[b3], 1u);
        }
    }

    __syncthreads();
    unsigned* dst = gh + ((unsigned)blockIdx.x << 10);
    for (int i = tid; i < 1024; i += 512) dst[i] = h[i];   // full overwrite
}

// ---------------------------------------------------------------------------
// 4) Reduce 256 partial hists + suffix-scan -> threshold bits in st[2].
// ---------------------------------------------------------------------------
__global__ __launch_bounds__(1024) void scan_kernel(
    const unsigned* __restrict__ gh, unsigned* st)
{
    __shared__ unsigned P[1024];
    const int t = threadIdx.x;
    unsigned s = 0;
    for (int p = 0; p < 256; ++p) s += gh[(p << 10) + t];
    P[t] = s;
    __syncthreads();
    for (int off = 1; off < 1024; off <<= 1) {
        unsigned v = P[t] + ((t + off < 1024) ? P[t + off] : 0u);
        __syncthreads();
        P[t] = v;
        __syncthreads();
    }
    if (P[t] >= KSEL && (t == 1023 || P[t + 1] < KSEL))
        st[2] = (0x3780u + (unsigned)t) << 16;   // lower edge of selected bin
}

// ---------------------------------------------------------------------------
// 5) Final: recompute p, threshold -> keep; else dropout (x1/0.9 or 0).
// ---------------------------------------------------------------------------
__global__ __launch_bounds__(256) void final_kernel(
    float* __restrict__ S, const float4* __restrict__ u4,
    const float2* __restrict__ stats, const unsigned* __restrict__ st)
{
    const int row = blockIdx.x;
    const float thr = __uint_as_float(st[2]);
    const float2 stt = stats[row];
    float4* r = (float4*)(S + (size_t)row * NN);
    const float4* u = u4 + (size_t)row * 1024;
    for (int i = threadIdx.x; i < 1024; i += 256) {
        float4 v = r[i];
        float4 uu = u[i];
        float4 o;
        float p;
        p = __expf(v.x - stt.x) * stt.y;
        o.x = (p >= thr) ? p : ((uu.x >= 0.1f) ? p * (1.0f / 0.9f) : 0.0f);
        p = __expf(v.y - stt.x) * stt.y;
        o.y = (p >= thr) ? p : ((uu.y >= 0.1f) ? p * (1.0f / 0.9f) : 0.0f);
        p = __expf(v.z - stt.x) * stt.y;
        o.z = (p >= thr) ? p : ((uu.z >= 0.1f) ? p * (1.0f / 0.9f) : 0.0f);
        p = __expf(v.w - stt.x) * stt.y;
        o.w = (p >= thr) ? p : ((uu.w >= 0.1f) ? p * (1.0f / 0.9f) : 0.0f);
        r[i] = o;
    }
}

extern "C" void kernel_launch(void* const* d_in, const int* in_sizes, int n_in,
                              void* d_out, int out_size, void* d_ws, size_t ws_size,
                              hipStream_t stream)
{
    const float* x  = (const float*)d_in[0];
    const float* WQ = (const float*)d_in[1];
    const float* WK = (const float*)d_in[2];
    const float* du = (const float*)d_in[3];
    float* out = (float*)d_out;
    char* ws = (char*)d_ws;

    float* Qp = (float*)(ws + OFF_P0);
    float* Kp = (float*)(ws + OFF_P2);
    short* Qhi = (short*)(ws + OFF_QH);
    short* Qlo = (short*)(ws + OFF_QL);
    short* Khi = (short*)(ws + OFF_KH);
    short* Klo = (short*)(ws + OFF_KL);
    float2* stats = (float2*)(ws + OFF_STATS);
    unsigned* hist = (unsigned*)(ws + OFF_H);   // reuses dead Qp region
    unsigned* st = (unsigned*)(ws + OFF_ST);

    proj_kernel<<<512, 512, 0, stream>>>(x, WQ, WK, Qp, Kp);
    combine_kernel<<<512, 256, 0, stream>>>(
        (const float4*)Qp, (const float4*)Kp, Qhi, Qlo, Khi, Klo);
    gemm_kernel<<<1024, 512, 0, stream>>>(Qhi, Qlo, Khi, Klo, out);
    histstat_kernel<<<256, 512, 0, stream>>>(out, stats, hist);
    scan_kernel<<<1, 1024, 0, stream>>>(hist, st);
    final_kernel<<<NN, 256, 0, stream>>>(out, (const float4*)du, stats, st);
}

// Round 8
// 111.367 us; speedup vs baseline: 1.3687x; 1.3687x over previous
//
#include <hip/hip_runtime.h>
#include <stdint.h>

// Problem constants
#define NN 4096
#define KSEL 1677721u            // int(4096*4096*0.1)
#define INV_SQRT_DK 0.17677669529663687f  // 1/sqrt(32)

// Workspace layout (bytes)
#define OFF_P0 0                      // Qpart fp32 [2][4096*128] = 4 MB (dead after combine)
#define OFF_P2 (4u<<20)               // Kpart fp32 [2][4096*128] = 4 MB
#define OFF_QH (8u<<20)               // bf16 1 MB
#define OFF_KH (9u<<20)               // bf16 1 MB
#define OFF_STATS (10u<<20)           // 4096 * float2 = 32 KB
// hist reuses the dead P0 region (written only after combine):
#define OFF_H   0u                    // 256 partial hists x 1024 u32 = 1 MB
#define OFF_H2  (1u<<20)              // 8 partial hists x 1024 u32 = 32 KB
#define OFF_ST  ((1u<<20) + 65536u)   // state: 4 u32
#define OFF_SB  (16u<<20)             // bf16 scores 32 MB (only if ws >= 48MB)
#define WS_NEED_B16 (48u<<20)
#define HALF_ELEMS 524288u            // 4096*128

typedef __attribute__((ext_vector_type(8))) short bf16x8;
typedef __attribute__((ext_vector_type(8))) unsigned short u16x8;
typedef __attribute__((ext_vector_type(4))) float f32x4;

static __device__ __forceinline__ short f2bf(float f) {
    unsigned u = __float_as_uint(f);
    unsigned r = (u + 0x7FFFu + ((u >> 16) & 1u)) >> 16;   // RNE
    return (short)r;
}
static __device__ __forceinline__ float bf2f(short h) {
    return __uint_as_float(((unsigned)(unsigned short)h) << 16);
}

// ---------------------------------------------------------------------------
// 1) Projection partial sums (fp32). Grid 512 = b(4) x ntile(64) x fhalf(2).
// ---------------------------------------------------------------------------
__global__ __launch_bounds__(512, 4) void proj_kernel(
    const float* __restrict__ x, const float* __restrict__ WQ,
    const float* __restrict__ WK,
    float* __restrict__ Qp, float* __restrict__ Kp)
{
    __shared__ float red[8 * 64 * 17];
    const int bx  = blockIdx.x;
    const int b   = bx >> 7;
    const int n0  = ((bx >> 1) & 63) << 6;
    const int fs  = bx & 1;
    const int tid = threadIdx.x;
    const int l   = tid & 63;
    const int w   = __builtin_amdgcn_readfirstlane(tid >> 6);
    const int n   = n0 + l;

    float* __restrict__ Qdst = Qp + (size_t)fs * HALF_ELEMS;
    float* __restrict__ Kdst = Kp + (size_t)fs * HALF_ELEMS;

    float accQ[32], accK[32];
#pragma unroll
    for (int j = 0; j < 32; ++j) { accQ[j] = 0.f; accK[j] = 0.f; }

    const int fg0 = fs * 32 + w * 4;
    const float* xp = x + (size_t)b * 3145728 + (size_t)fg0 * 49152 + (size_t)n * 12;

    for (int f = 0; f < 4; ++f) {
        float4 a0 = *(const float4*)(xp);
        float4 a1 = *(const float4*)(xp + 4);
        float4 a2 = *(const float4*)(xp + 8);
        const float xv[12] = {a0.x, a0.y, a0.z, a0.w,
                              a1.x, a1.y, a1.z, a1.w,
                              a2.x, a2.y, a2.z, a2.w};
        const int fg = fg0 + f;
#pragma unroll
        for (int t = 0; t < 12; ++t) {
            const float* __restrict__ wq = WQ + (size_t)(((t << 6) + fg) << 5);
            const float* __restrict__ wk = WK + (size_t)(((t << 6) + fg) << 5);
            const float xt = xv[t];
#pragma unroll
            for (int j = 0; j < 32; ++j) {
                accQ[j] = fmaf(xt, wq[j], accQ[j]);
                accK[j] = fmaf(xt, wk[j], accK[j]);
            }
        }
        xp += 49152;
    }

    for (int p = 0; p < 4; ++p) {
        const float* src = (p < 2) ? accQ : accK;
        const int off = (p & 1) << 4;
        float* rp = &red[(w * 64 + l) * 17];
#pragma unroll
        for (int j = 0; j < 16; ++j) rp[j] = src[off + j];
        __syncthreads();
#pragma unroll
        for (int h = 0; h < 2; ++h) {
            int o = tid + h * 512;
            int r_ = o >> 4, c = o & 15;
            float s = 0.f;
#pragma unroll
            for (int w2 = 0; w2 < 8; ++w2) s += red[(w2 * 64 + r_) * 17 + c];
            size_t idx = (size_t)(n0 + r_) * 128 + (b << 5) + ((p & 1) << 4) + c;
            if (p < 2) Qdst[idx] = s; else Kdst[idx] = s;
        }
        __syncthreads();
    }
}

// ---------------------------------------------------------------------------
// 1b) Combine f-halves, scale Q, round to bf16 (single, no hi/lo split).
//     Grid 512x256 (131072 float4 slots per matrix).
// ---------------------------------------------------------------------------
__global__ __launch_bounds__(256) void combine_kernel(
    const float4* __restrict__ Qp, const float4* __restrict__ Kp,
    short* __restrict__ Qh, short* __restrict__ Kh)
{
    const size_t i = (size_t)blockIdx.x * 256 + threadIdx.x;
    float4 q0 = Qp[i], q1 = Qp[i + HALF_ELEMS / 4];
    float4 k0 = Kp[i], k1 = Kp[i + HALF_ELEMS / 4];
    short4 qh, kh;
    qh.x = f2bf((q0.x + q1.x) * INV_SQRT_DK);
    qh.y = f2bf((q0.y + q1.y) * INV_SQRT_DK);
    qh.z = f2bf((q0.z + q1.z) * INV_SQRT_DK);
    qh.w = f2bf((q0.w + q1.w) * INV_SQRT_DK);
    kh.x = f2bf(k0.x + k1.x);
    kh.y = f2bf(k0.y + k1.y);
    kh.z = f2bf(k0.z + k1.z);
    kh.w = f2bf(k0.w + k1.w);
    *(short4*)(Qh + 4 * i) = qh;
    *(short4*)(Kh + 4 * i) = kh;
}

// ---------------------------------------------------------------------------
// 2) S = Q @ K^T via MFMA 16x16x32 bf16 (single product). 128x128 tile per
//    256-thread block, wave tile 64x64 (4x4 frags), explicit 2-deep register
//    ping-pong prefetch over the 4 k-steps. Operands 2 MB -> L2-resident.
// ---------------------------------------------------------------------------
template<bool B16>
__global__ __launch_bounds__(256, 3) void gemm_kernel(
    const short* __restrict__ Qh, const short* __restrict__ Kh, void* Sv)
{
    const int bi = blockIdx.x >> 5, bj = blockIdx.x & 31;
    const int tid = threadIdx.x;
    const int w = tid >> 6, l = tid & 63;
    const int m0 = bi * 128 + (w >> 1) * 64;
    const int n0 = bj * 128 + (w & 1) * 64;
    const int lr = l & 15;
    const int kg = (l >> 4) * 8;

    f32x4 acc[4][4];
#pragma unroll
    for (int i = 0; i < 4; ++i)
#pragma unroll
        for (int j = 0; j < 4; ++j) acc[i][j] = (f32x4){0.f, 0.f, 0.f, 0.f};

    bf16x8 aA[4], bA[4], aB[4], bB[4];

    auto LD = [&](bf16x8* A, bf16x8* B, int k0) {
#pragma unroll
        for (int i = 0; i < 4; ++i) {
            A[i] = *(const bf16x8*)(Qh + (size_t)(m0 + i * 16 + lr) * 128 + k0 + kg);
            B[i] = *(const bf16x8*)(Kh + (size_t)(n0 + i * 16 + lr) * 128 + k0 + kg);
        }
    };
    auto DOMFMA = [&](bf16x8* A, bf16x8* B) {
#pragma unroll
        for (int i = 0; i < 4; ++i)
#pragma unroll
            for (int j = 0; j < 4; ++j)
                acc[i][j] = __builtin_amdgcn_mfma_f32_16x16x32_bf16(A[i], B[j], acc[i][j], 0, 0, 0);
    };

    LD(aA, bA, 0);
    LD(aB, bB, 32);
    DOMFMA(aA, bA);  LD(aA, bA, 64);
    DOMFMA(aB, bB);  LD(aB, bB, 96);
    DOMFMA(aA, bA);
    DOMFMA(aB, bB);

    // C/D mapping (m89-verified): col = lane&15, row = (lane>>4)*4 + reg
#pragma unroll
    for (int i = 0; i < 4; ++i) {
        int rowb = m0 + i * 16 + (l >> 4) * 4;
#pragma unroll
        for (int j = 0; j < 4; ++j) {
            int col = n0 + j * 16 + (l & 15);
#pragma unroll
            for (int r = 0; r < 4; ++r) {
                if constexpr (B16)
                    ((unsigned short*)Sv)[(size_t)(rowb + r) * NN + col] =
                        (unsigned short)f2bf(acc[i][j][r]);
                else
                    ((float*)Sv)[(size_t)(rowb + r) * NN + col] = acc[i][j][r];
            }
        }
    }
}

// ---------------------------------------------------------------------------
// 3) Fused row stats + histogram. One wave per row, row in registers.
//    Each block OWNS partial-hist slot blockIdx.x (full overwrite, no memset).
// ---------------------------------------------------------------------------
template<bool B16>
__global__ __launch_bounds__(512) void histstat_kernel(
    const void* __restrict__ Sv, float2* __restrict__ stats,
    unsigned* __restrict__ gh)
{
    __shared__ unsigned h[1024];
    const int tid = threadIdx.x;
    const int l = tid & 63;
    const int w = tid >> 6;

    for (int i = tid; i < 1024; i += 512) h[i] = 0;
    __syncthreads();

#pragma unroll
    for (int r = 0; r < 2; ++r) {
        const int row = (blockIdx.x << 4) + (r << 3) + w;

        float v[64];
        if constexpr (B16) {
            const u16x8* rp = (const u16x8*)((const unsigned short*)Sv + (size_t)row * NN);
#pragma unroll
            for (int j = 0; j < 8; ++j) {
                u16x8 e = rp[l + (j << 6)];
#pragma unroll
                for (int i = 0; i < 8; ++i) v[j * 8 + i] = bf2f((short)e[i]);
            }
        } else {
            const float4* rp = (const float4*)((const float*)Sv + (size_t)row * NN);
#pragma unroll
            for (int j = 0; j < 16; ++j) {
                float4 t = rp[l + (j << 6)];
                v[j * 4 + 0] = t.x; v[j * 4 + 1] = t.y;
                v[j * 4 + 2] = t.z; v[j * 4 + 3] = t.w;
            }
        }

        float m = -3.4e38f;
#pragma unroll
        for (int j = 0; j < 64; ++j) m = fmaxf(m, v[j]);
#pragma unroll
        for (int off = 32; off; off >>= 1) m = fmaxf(m, __shfl_xor(m, off));

        float s = 0.f;
#pragma unroll
        for (int j = 0; j < 64; ++j) { v[j] = __expf(v[j] - m); s += v[j]; }
#pragma unroll
        for (int off = 32; off; off >>= 1) s += __shfl_xor(s, off);
        const float inv = 1.0f / s;
        if (l == 0) stats[row] = make_float2(m, inv);

#pragma unroll
        for (int j = 0; j < 64; ++j) {
            int b0 = min(max((int)(__float_as_uint(v[j] * inv) >> 16) - 0x3780, 0), 1023);
            atomicAdd(&h[b0], 1u);
        }
    }

    __syncthreads();
    unsigned* dst = gh + ((unsigned)blockIdx.x << 10);
    for (int i = tid; i < 1024; i += 512) dst[i] = h[i];   // full overwrite
}

// ---------------------------------------------------------------------------
// 4a) Pre-reduce 256 partials -> 8 (spread over 8 CUs).
// ---------------------------------------------------------------------------
__global__ __launch_bounds__(1024) void reduce_kernel(
    const unsigned* __restrict__ gh, unsigned* __restrict__ gh2)
{
    const int t = threadIdx.x, b = blockIdx.x;
    unsigned s = 0;
    for (int p = 0; p < 32; ++p) s += gh[((unsigned)(b * 32 + p) << 10) + t];
    gh2[((unsigned)b << 10) + t] = s;
}

// ---------------------------------------------------------------------------
// 4b) Reduce 8 partials + suffix-scan -> threshold bits in st[2].
// ---------------------------------------------------------------------------
__global__ __launch_bounds__(1024) void scan_kernel(
    const unsigned* __restrict__ gh2, unsigned* st)
{
    __shared__ unsigned P[1024];
    const int t = threadIdx.x;
    unsigned s = 0;
#pragma unroll
    for (int p = 0; p < 8; ++p) s += gh2[(p << 10) + t];
    P[t] = s;
    __syncthreads();
    for (int off = 1; off < 1024; off <<= 1) {
        unsigned v = P[t] + ((t + off < 1024) ? P[t + off] : 0u);
        __syncthreads();
        P[t] = v;
        __syncthreads();
    }
    if (P[t] >= KSEL && (t == 1023 || P[t + 1] < KSEL))
        st[2] = (0x3780u + (unsigned)t) << 16;   // lower edge of selected bin
}

// ---------------------------------------------------------------------------
// 5) Final: recompute p, threshold -> keep; else dropout (x1/0.9 or 0).
// ---------------------------------------------------------------------------
template<bool B16>
__global__ __launch_bounds__(256) void final_kernel(
    const void* __restrict__ Sv, float* __restrict__ out,
    const float4* __restrict__ u4,
    const float2* __restrict__ stats, const unsigned* __restrict__ st)
{
    const int row = blockIdx.x;
    const float thr = __uint_as_float(st[2]);
    const float2 stt = stats[row];
    float4* o4 = (float4*)(out + (size_t)row * NN);
    const float4* u = u4 + (size_t)row * 1024;
    for (int i = threadIdx.x; i < 1024; i += 256) {
        float4 v;
        if constexpr (B16) {
            ushort4 s4 = ((const ushort4*)((const unsigned short*)Sv + (size_t)row * NN))[i];
            v.x = bf2f((short)s4.x); v.y = bf2f((short)s4.y);
            v.z = bf2f((short)s4.z); v.w = bf2f((short)s4.w);
        } else {
            v = ((const float4*)((const float*)Sv + (size_t)row * NN))[i];
        }
        float4 uu = u[i];
        float4 o;
        float p;
        p = __expf(v.x - stt.x) * stt.y;
        o.x = (p >= thr) ? p : ((uu.x >= 0.1f) ? p * (1.0f / 0.9f) : 0.0f);
        p = __expf(v.y - stt.x) * stt.y;
        o.y = (p >= thr) ? p : ((uu.y >= 0.1f) ? p * (1.0f / 0.9f) : 0.0f);
        p = __expf(v.z - stt.x) * stt.y;
        o.z = (p >= thr) ? p : ((uu.z >= 0.1f) ? p * (1.0f / 0.9f) : 0.0f);
        p = __expf(v.w - stt.x) * stt.y;
        o.w = (p >= thr) ? p : ((uu.w >= 0.1f) ? p * (1.0f / 0.9f) : 0.0f);
        o4[i] = o;
    }
}

extern "C" void kernel_launch(void* const* d_in, const int* in_sizes, int n_in,
                              void* d_out, int out_size, void* d_ws, size_t ws_size,
                              hipStream_t stream)
{
    const float* x  = (const float*)d_in[0];
    const float* WQ = (const float*)d_in[1];
    const float* WK = (const float*)d_in[2];
    const float* du = (const float*)d_in[3];
    float* out = (float*)d_out;
    char* ws = (char*)d_ws;

    float* Qp = (float*)(ws + OFF_P0);
    float* Kp = (float*)(ws + OFF_P2);
    short* Qh = (short*)(ws + OFF_QH);
    short* Kh = (short*)(ws + OFF_KH);
    float2* stats = (float2*)(ws + OFF_STATS);
    unsigned* hist = (unsigned*)(ws + OFF_H);    // reuses dead P0 region
    unsigned* gh2  = (unsigned*)(ws + OFF_H2);
    unsigned* st   = (unsigned*)(ws + OFF_ST);

    proj_kernel<<<512, 512, 0, stream>>>(x, WQ, WK, Qp, Kp);
    combine_kernel<<<512, 256, 0, stream>>>(
        (const float4*)Qp, (const float4*)Kp, Qh, Kh);

    const bool b16 = (ws_size >= (size_t)WS_NEED_B16);   // fixed per process -> graph-safe
    if (b16) {
        void* Sb = (void*)(ws + OFF_SB);
        gemm_kernel<true><<<1024, 256, 0, stream>>>(Qh, Kh, Sb);
        histstat_kernel<true><<<256, 512, 0, stream>>>(Sb, stats, hist);
        reduce_kernel<<<8, 1024, 0, stream>>>(hist, gh2);
        scan_kernel<<<1, 1024, 0, stream>>>(gh2, st);
        final_kernel<true><<<NN, 256, 0, stream>>>(Sb, out, (const float4*)du, stats, st);
    } else {
        gemm_kernel<false><<<1024, 256, 0, stream>>>(Qh, Kh, (void*)out);
        histstat_kernel<false><<<256, 512, 0, stream>>>((void*)out, stats, hist);
        reduce_kernel<<<8, 1024, 0, stream>>>(hist, gh2);
        scan_kernel<<<1, 1024, 0, stream>>>(gh2, st);
        final_kernel<false><<<NN, 256, 0, stream>>>((void*)out, out, (const float4*)du, stats, st);
    }
}